// Round 4
// baseline (565.207 us; speedup 1.0000x reference)
//
#include <hip/hip_runtime.h>
#include <hip/hip_cooperative_groups.h>

namespace cg = cooperative_groups;

// RoleSensitiveEmbedding: out[t,:] = W_{role[t]} @ emb[ids[t],:]
// Partition tokens by role -> bf16 MFMA GEMM per region (half the FLOPs of
// reference's compute-both-and-select).
// R4: memset+perm+wconv+gather fused into ONE cooperative kernel (5 graph
//     nodes -> 2), block-aggregated atomics (128 global atomics vs 512
//     contended wave-ops). GEMM byte-identical to R3 for attribution.

#define M_TOK   16384
#define DIM     1024
#define MT      128                 // gemm m-tile rows
#define NTIL    130                 // ceil(n0/128)+ceil(n1/128) <= 130 always
#define XROWS   (NTIL * MT)         // 16640
#define BK      64
#define NB      1024                // coop pre-kernel grid (4 blocks/CU, co-resident)

typedef __attribute__((ext_vector_type(8))) short short8;
typedef __attribute__((ext_vector_type(4))) float f32x4;

// ---- workspace layout (bytes) ----
#define OFF_PERM 256
#define OFF_WB   66816
#define OFF_X    4261120
// total ~38.3 MB

static __device__ __forceinline__ unsigned short f2bf(float f) {
    unsigned int u = __float_as_uint(f);
    u += 0x7fffu + ((u >> 16) & 1u);   // round-to-nearest-even
    return (unsigned short)(u >> 16);
}

// Cooperative: phase0 zero cnt | phase1 perm (blocks 0..63) + wconv (64..NB-1)
//            | phase2 gather emb rows -> bf16 X (grid-stride)
__global__ void k_pre(const int* __restrict__ role, const int* __restrict__ ids,
                      const float* __restrict__ emb,
                      const float* __restrict__ W0, const float* __restrict__ W1,
                      int* perm, int* cnt,
                      unsigned short* __restrict__ Wb, unsigned short* __restrict__ X) {
    cg::grid_group grid = cg::this_grid();
    __shared__ int lc[2];        // block-local role counts
    __shared__ int wbase[4][2];  // per-wave base within block
    __shared__ int gbase[2];     // block's base within global

    int b = blockIdx.x, t = threadIdx.x;

    // ---- phase 0: zero the global counters ----
    if (b == 0 && t < 2) cnt[t] = 0;
    grid.sync();

    // ---- phase 1 ----
    if (b < 64) {
        // role partition, block-aggregated two-sided packing
        int tok = b * 256 + t;
        int r = (role[tok] == 1) ? 1 : 0;
        if (t < 2) lc[t] = 0;
        __syncthreads();
        int wv = t >> 6, lane = t & 63;
        unsigned long long m = __ballot(r);
        int c1 = __popcll(m);
        unsigned long long lower = m & ((1ull << lane) - 1ull);
        int rank1 = __popcll(lower);
        int rank0 = lane - rank1;
        if (lane == 0) {
            wbase[wv][1] = atomicAdd(&lc[1], c1);
            wbase[wv][0] = atomicAdd(&lc[0], 64 - c1);
        }
        __syncthreads();
        if (t == 0) {
            gbase[0] = atomicAdd(&cnt[0], lc[0]);
            gbase[1] = atomicAdd(&cnt[1], lc[1]);
        }
        __syncthreads();
        int idx = r ? (gbase[1] + wbase[wv][1] + rank1)
                    : (gbase[0] + wbase[wv][0] + rank0);
        int row = r ? (XROWS - 1 - idx) : idx;
        perm[row] = tok;
    } else {
        // W0|W1 fp32 -> bf16, grid-stride over 524288 float4s
        for (int i = (b - 64) * 256 + t; i < 524288; i += (NB - 64) * 256) {
            int idx = i * 4;
            const float* src = (idx < 1048576) ? (W0 + idx) : (W1 + (idx - 1048576));
            float4 f = *(const float4*)src;
            *(ushort4*)(Wb + idx) =
                make_ushort4(f2bf(f.x), f2bf(f.y), f2bf(f.z), f2bf(f.w));
        }
    }
    grid.sync();

    // ---- phase 2: gather (one row per block-iteration) ----
    int n0 = cnt[0], n1 = cnt[1];
    for (int row = b; row < XROWS; row += NB) {
        if (row >= n0 && row < XROWS - n1) continue;   // gap row
        int p  = perm[row];
        int id = ids[p];
        float4 f = *(const float4*)(emb + (size_t)id * DIM + t * 4);
        *(ushort4*)(X + (size_t)row * DIM + t * 4) =
            make_ushort4(f2bf(f.x), f2bf(f.y), f2bf(f.z), f2bf(f.w));
    }
}

// 128x128 tile GEMM, C = A * B^T: A = X[XROWS,1024] bf16, B^T = W_e rows.
// LDS staged via global_load_lds width=16, XOR swizzle kc^(row&7) on the
// global-gather side so ds_read_b128 fragment reads stay ~conflict-free.
// (byte-identical to R3)
__global__ __launch_bounds__(256, 3)
void k_gemm(const unsigned short* __restrict__ Xu, const unsigned short* __restrict__ Wbu,
            const int* __restrict__ perm, const int* __restrict__ cnt,
            float* __restrict__ out) {
    __shared__ short As[MT * BK];      // 16 KB
    __shared__ short Bs[MT * BK];      // 16 KB

    // XCD swizzle: all 8 n-tiles of an m-tile share one XCD's L2
    int f  = blockIdx.x;
    int mt = ((f >> 6) << 3) | (f & 7);
    int nt = (f >> 3) & 7;
    if (mt >= NTIL) return;

    int n0 = cnt[0], n1 = cnt[1];
    int T0 = (n0 + 127) >> 7, T1 = (n1 + 127) >> 7;
    int e, lo, hi;
    if (mt < T0)              { e = 0; lo = 0;            hi = n0;    }
    else if (mt >= NTIL - T1) { e = 1; lo = XROWS - n1;   hi = XROWS; }
    else return;                           // gap tile

    const short* Ag = (const short*)Xu + (size_t)mt * MT * DIM;
    const short* Bg = (const short*)Wbu + (size_t)e * DIM * DIM + (size_t)nt * MT * DIM;

    int tid  = threadIdx.x;
    int lane = tid & 63;
    int w    = tid >> 6;         // wave 0..3
    int wm   = w & 1, wn = w >> 1;
    int quad = lane >> 4, lq = lane & 15;

    f32x4 acc[4][4] = {};

    for (int k0 = 0; k0 < DIM; k0 += BK) {
#pragma unroll
        for (int i = 0; i < 4; ++i) {
            int q   = w * 4 + i;          // wave-uniform issue id 0..15
            int s   = q * 64 + lane;      // 16B slot index in tile
            int row = s >> 3;
            int kc  = (s & 7) ^ (row & 7);   // swizzled source k-chunk
            __builtin_amdgcn_global_load_lds(
                (const __attribute__((address_space(1))) unsigned int*)(Ag + (size_t)row * DIM + k0 + kc * 8),
                (__attribute__((address_space(3))) unsigned int*)(&As[s * 8]),
                16, 0, 0);
            __builtin_amdgcn_global_load_lds(
                (const __attribute__((address_space(1))) unsigned int*)(Bg + (size_t)row * DIM + k0 + kc * 8),
                (__attribute__((address_space(3))) unsigned int*)(&Bs[s * 8]),
                16, 0, 0);
        }
        __syncthreads();

#pragma unroll
        for (int s = 0; s < 2; ++s) {
            short8 av[4], bv[4];
            int s4q = s * 4 + quad;
#pragma unroll
            for (int i = 0; i < 4; ++i) {
                int ra = wm * 64 + i * 16 + lq;
                av[i] = *(const short8*)&As[(ra * 8 + (s4q ^ (ra & 7))) * 8];
                int rb = wn * 64 + i * 16 + lq;
                bv[i] = *(const short8*)&Bs[(rb * 8 + (s4q ^ (rb & 7))) * 8];
            }
#pragma unroll
            for (int i = 0; i < 4; ++i)
#pragma unroll
                for (int j = 0; j < 4; ++j)
                    acc[i][j] = __builtin_amdgcn_mfma_f32_16x16x32_bf16(
                        av[i], bv[j], acc[i][j], 0, 0, 0);
        }
        __syncthreads();
    }

    // epilogue: C/D map m = quad*4+reg, n = lq; scatter rows to out[token,:]
    int colbase = nt * 128 + wn * 64 + lq;
#pragma unroll
    for (int i = 0; i < 4; ++i) {
#pragma unroll
        for (int r = 0; r < 4; ++r) {
            int mrow = mt * MT + wm * 64 + i * 16 + quad * 4 + r;
            if (mrow < lo || mrow >= hi) continue;   // gap row (bounds, not sentinel)
            int token = perm[mrow];
            float* o = out + (size_t)token * DIM + colbase;
#pragma unroll
            for (int j = 0; j < 4; ++j)
                o[j * 16] = acc[i][j][r];
        }
    }
}

extern "C" void kernel_launch(void* const* d_in, const int* in_sizes, int n_in,
                              void* d_out, int out_size, void* d_ws, size_t ws_size,
                              hipStream_t stream) {
    const int*   ids  = (const int*)d_in[0];
    const int*   role = (const int*)d_in[1];
    const float* emb  = (const float*)d_in[2];
    const float* W0   = (const float*)d_in[3];
    const float* W1   = (const float*)d_in[4];
    float*       out  = (float*)d_out;

    char* ws = (char*)d_ws;
    int* cnt  = (int*)ws;
    int* perm = (int*)(ws + OFF_PERM);
    unsigned short* Wb = (unsigned short*)(ws + OFF_WB);
    unsigned short* X  = (unsigned short*)(ws + OFF_X);

    void* args[] = { (void*)&role, (void*)&ids, (void*)&emb, (void*)&W0, (void*)&W1,
                     (void*)&perm, (void*)&cnt, (void*)&Wb, (void*)&X };
    hipLaunchCooperativeKernel((const void*)k_pre, dim3(NB), dim3(256), args, 0, stream);
    k_gemm<<<1088, 256, 0, stream>>>(X, Wb, perm, cnt, out);
}